// Round 4
// baseline (595.452 us; speedup 1.0000x reference)
//
#include <hip/hip_runtime.h>
#include <cstdint>
#include <cstddef>

// ---------------------------------------------------------------------------
// SelfModifyingRecurrent: B=8192, E=1024, L=3
//   * h_prev stays ZERO -> gh = b_hh (const), no W_hh GEMM
//   * weight modification is rank-1 -> gi += cond * 0.01*dot(cur, mean_sig)
// f16 MFMA (16x16x32) fp32-accum. LDS XOR-swizzle via pre-swizzled global
// source + swizzled ds_read. gemm_gru: 2-phase double-buffered K-loop
// (STAGE(next) issued before compute(cur); ONE barrier per K-step) to hide
// global_load_lds latency — the R3 counters showed a latency stall (MfmaUtil
// 20%, VALU 23%, HBM 12%, occ 23%) from the stage->drain->compute structure.
// ---------------------------------------------------------------------------

#define BSZ 8192
#define ESZ 1024

typedef _Float16 f16x8 __attribute__((ext_vector_type(8)));
typedef float    f32x4 __attribute__((ext_vector_type(4)));
typedef unsigned short u16;
typedef u16 u16x4 __attribute__((ext_vector_type(4)));

__device__ __forceinline__ u16 f2h(float f) {
    _Float16 h = (_Float16)f;
    return __builtin_bit_cast(u16, h);
}
__device__ __forceinline__ float h2f(u16 h) {
    return (float)__builtin_bit_cast(_Float16, h);
}

__device__ __forceinline__ void gload16(const void* g, void* l) {
    __builtin_amdgcn_global_load_lds((const __attribute__((address_space(1))) void*)g,
                                     (__attribute__((address_space(3))) void*)l,
                                     16, 0, 0);
}

// swizzled LDS u16 index: row-stride 64 u16 (128B), chunk = 8-u16 (16B) slot 0..7
__device__ __forceinline__ int swzi(int row, int chunk) {
    return (row << 6) + (((chunk ^ row) & 7) << 3);
}

__device__ __forceinline__ float sigmoidf_(float x) {
    return 1.f / (1.f + __expf(-x));
}
__device__ __forceinline__ float tanhf_(float x) {
    float cx = fminf(fmaxf(x, -15.f), 15.f);
    float e = __expf(2.f * cx);
    return (e - 1.f) / (e + 1.f);
}

// ---------------------------------------------------------------------------
// fused fp32 -> f16 conversion for Wih, W1, W2, x (one launch)
// ---------------------------------------------------------------------------
#define N4_WIH (3 * 3072 * 1024 / 4)
#define N4_W1  (3 * 512 * 1024 / 4)
#define N4_W2  (3 * 1024 * 512 / 4)
#define N4_X   (BSZ * ESZ / 4)

__global__ void cvt_all_kernel(const float* __restrict__ Wih, const float* __restrict__ W1,
                               const float* __restrict__ W2, const float* __restrict__ x,
                               u16* __restrict__ oWih, u16* __restrict__ oW1,
                               u16* __restrict__ oW2, u16* __restrict__ ox) {
    int i = blockIdx.x * 256 + threadIdx.x;
    const float* in;
    u16* out;
    if (i < N4_WIH) { in = Wih; out = oWih; }
    else if (i < N4_WIH + N4_W1) { i -= N4_WIH; in = W1; out = oW1; }
    else if (i < N4_WIH + N4_W1 + N4_W2) { i -= N4_WIH + N4_W1; in = W2; out = oW2; }
    else { i -= N4_WIH + N4_W1 + N4_W2; if (i >= N4_X) return; in = x; out = ox; }
    f32x4 v = ((const f32x4*)in)[i];
    u16x4 o;
    o.x = f2h(v.x); o.y = f2h(v.y); o.z = f2h(v.z); o.w = f2h(v.w);
    ((u16x4*)out)[i] = o;
}

// ---------------------------------------------------------------------------
// Gate kernel (reads f16 cur): per row r:
//   gate_r = sigmoid(dot(cur_r, Wg) + bg)       -> atomic sum into gsum
//   sdot_r = dot(cur_r, colsum_sig)*(0.01/B)
// One wave per row, 4 rows per block; fp32 accumulate.
// ---------------------------------------------------------------------------
__global__ void gate_kernel(const u16* __restrict__ cur, const float* __restrict__ Wg,
                            const float* __restrict__ bg, const float* __restrict__ colsum,
                            float* __restrict__ gsum, float* __restrict__ sdot) {
    const int wid = threadIdx.x >> 6, lane = threadIdx.x & 63;
    const int row = blockIdx.x * 4 + wid;
    const u16* cr = cur + (size_t)row * ESZ;
    float pg = 0.f, pm = 0.f;
#pragma unroll
    for (int h = 0; h < 2; h++) {
        int base = lane * 16 + h * 8;
        f16x8 cv = *(const f16x8*)(cr + base);
#pragma unroll
        for (int q = 0; q < 2; q++) {
            f32x4 wv = *(const f32x4*)(Wg + base + q * 4);
            f32x4 mv = *(const f32x4*)(colsum + base + q * 4);
#pragma unroll
            for (int e = 0; e < 4; e++) {
                float c = (float)cv[q * 4 + e];
                pg += c * wv[e];
                pm += c * mv[e];
            }
        }
    }
#pragma unroll
    for (int s = 32; s >= 1; s >>= 1) {
        pg += __shfl_xor(pg, s);
        pm += __shfl_xor(pm, s);
    }
    __shared__ float gp[4];
    if (lane == 0) {
        gp[wid] = sigmoidf_(pg + bg[0]);
        sdot[row] = pm * (0.01f / 8192.f);
    }
    __syncthreads();
    if (threadIdx.x == 0) atomicAdd(gsum, gp[0] + gp[1] + gp[2] + gp[3]);
}

// ---------------------------------------------------------------------------
// Generic GEMM: C[M,N] = act(A[M,K] @ W[N,K]^T + bias)
// ACT=0: relu -> f16 out.  ACT=1: tanh -> f16 out + fp32 column-sum atomics.
// 128x128 tile, BK=64, 4 waves (2x2), 16x16x32 f16 MFMA, swizzled staging.
// (Left single-buffered: ~3 blocks/CU resident -> cross-block overlap; m99
//  evidence says explicit dbuf is neutral there.)
// ---------------------------------------------------------------------------
template <int ACT>
__global__ void __launch_bounds__(256, 2) gemm_act_kernel(
    const u16* __restrict__ A, const u16* __restrict__ W,
    const float* __restrict__ bias, u16* __restrict__ outp,
    float* __restrict__ colsum, int N, int K) {
    __shared__ u16 lA[128 * 64];
    __shared__ u16 lB[128 * 64];
    const int t = threadIdx.x;
    const int m0 = blockIdx.y * 128, n0 = blockIdx.x * 128;
    const int wid = t >> 6, lane = t & 63;
    const int waver = wid >> 1, wavec = wid & 1;
    const int lrow = lane & 15, lk = lane >> 4;

    f32x4 acc[4][4] = {};

    for (int k0 = 0; k0 < K; k0 += 64) {
        __syncthreads();
#pragma unroll
        for (int i = 0; i < 4; i++) {
            int eo = i * 2048 + t * 8;
            int r = eo >> 6;
            int gc = (((eo >> 3) ^ r) & 7) << 3;  // inverse(=same) swizzle on source
            gload16(A + (size_t)(m0 + r) * K + k0 + gc, &lA[eo]);
            gload16(W + (size_t)(n0 + r) * K + k0 + gc, &lB[eo]);
        }
        __syncthreads();
#pragma unroll
        for (int kk = 0; kk < 2; kk++) {
            f16x8 af[4], bf[4];
#pragma unroll
            for (int m = 0; m < 4; m++)
                af[m] = *(const f16x8*)&lA[swzi(waver * 64 + m * 16 + lrow, kk * 4 + lk)];
#pragma unroll
            for (int n = 0; n < 4; n++)
                bf[n] = *(const f16x8*)&lB[swzi(wavec * 64 + n * 16 + lrow, kk * 4 + lk)];
#pragma unroll
            for (int m = 0; m < 4; m++)
#pragma unroll
                for (int n = 0; n < 4; n++)
                    acc[m][n] = __builtin_amdgcn_mfma_f32_16x16x32_f16(af[m], bf[n], acc[m][n], 0, 0, 0);
        }
    }

#pragma unroll
    for (int n = 0; n < 4; n++) {
        int c = n0 + wavec * 64 + n * 16 + lrow;
        float bv = bias[c];
        float cs = 0.f;
#pragma unroll
        for (int m = 0; m < 4; m++) {
            int rbase = m0 + waver * 64 + m * 16 + lk * 4;
#pragma unroll
            for (int j = 0; j < 4; j++) {
                float v = acc[m][n][j] + bv;
                if (ACT == 0) {
                    v = v > 0.f ? v : 0.f;
                    outp[(size_t)(rbase + j) * N + c] = f2h(v);
                } else {
                    float tv = tanhf_(v);
                    outp[(size_t)(rbase + j) * N + c] = f2h(tv);
                    cs += tv;
                }
            }
        }
        if (ACT == 1) {
            cs += __shfl_xor(cs, 16);
            cs += __shfl_xor(cs, 32);
            if (lane < 16) atomicAdd(&colsum[c], cs);
        }
    }
}

// ---------------------------------------------------------------------------
// Fused GEMM3 + GRU epilogue, 2-phase double-buffered.
// 128 rows x 64 sig-cols x 3 gate groups per block.
// K-loop per step: ONE __syncthreads (drains prev STAGE vmcnt + prev ds_reads),
// then issue STAGE(next tile) into the other buffer, then ds_read+MFMA on the
// current buffer -> HBM latency hides under the 48 MFMAs.
//   i_* = gi_* + b_ih[*] + cond*sdot[row]
//   r = sig(i_r + b_hh_r); z = sig(i_z + b_hh_z); n = tanh(i_n + r*b_hh_n)
//   cur_out = (1-z)*n + sig_mlp[row,c]
// ---------------------------------------------------------------------------
__global__ void __launch_bounds__(256, 2) gemm_gru_kernel(
    const u16* __restrict__ Ab, const u16* __restrict__ Wb,
    const float* __restrict__ bih, const float* __restrict__ bhh,
    const u16* __restrict__ sig, const float* __restrict__ sdot,
    const float* __restrict__ gsum, float* __restrict__ curf_out,
    u16* __restrict__ curb_out) {
    __shared__ u16 lA[2][128 * 64];
    __shared__ u16 lB[2][3][64 * 64];
    const int t = threadIdx.x;
    // XCD-bijective remap: each XCD owns 2 col-blocks x all 64 row-panels so
    // its W_ih working set (~786 KB) stays L2-resident.
    const int hw = blockIdx.y * 16 + blockIdx.x;
    const int xcd = hw & 7, idx = hw >> 3;
    const int m0 = (idx >> 1) * 128, c0 = ((xcd << 1) | (idx & 1)) * 64;
    const int wid = t >> 6, lane = t & 63;
    const int waver = wid >> 1, wavec = wid & 1;
    const int lrow = lane & 15, lk = lane >> 4;
    const int K = ESZ, E = ESZ;

    // Per-thread staging addresses (fixed across K-steps except k0)
    const int eoA = t * 8;                 // i-loop adds i*2048
    f32x4 acc[4][6] = {};

    auto STAGE = [&](int buf, int k0) {
#pragma unroll
        for (int i = 0; i < 4; i++) {
            int eo = i * 2048 + eoA;
            int r = eo >> 6;
            int gc = (((eo >> 3) ^ r) & 7) << 3;
            gload16(Ab + (size_t)(m0 + r) * K + k0 + gc, &lA[buf][eo]);
        }
#pragma unroll
        for (int g = 0; g < 3; g++)
#pragma unroll
            for (int i = 0; i < 2; i++) {
                int eo = i * 2048 + eoA;
                int r = eo >> 6;
                int gc = (((eo >> 3) ^ r) & 7) << 3;
                gload16(Wb + (size_t)(g * 1024 + c0 + r) * K + k0 + gc, &lB[buf][g][eo]);
            }
    };

    STAGE(0, 0);  // prologue: issue tile 0, no wait
    int cur = 0;
    for (int kt = 0; kt < 16; ++kt) {
        __syncthreads();  // vmcnt(0): buf[cur] staged; lgkmcnt(0): prev reads done
        if (kt < 15) STAGE(cur ^ 1, (kt + 1) * 64);
#pragma unroll
        for (int kk = 0; kk < 2; kk++) {
            f16x8 af[4];
#pragma unroll
            for (int m = 0; m < 4; m++)
                af[m] = *(const f16x8*)&lA[cur][swzi(waver * 64 + m * 16 + lrow, kk * 4 + lk)];
#pragma unroll
            for (int g = 0; g < 3; g++) {
#pragma unroll
                for (int n = 0; n < 2; n++) {
                    f16x8 bf = *(const f16x8*)&lB[cur][g][swzi(wavec * 32 + n * 16 + lrow, kk * 4 + lk)];
#pragma unroll
                    for (int m = 0; m < 4; m++)
                        acc[m][g * 2 + n] =
                            __builtin_amdgcn_mfma_f32_16x16x32_f16(af[m], bf, acc[m][g * 2 + n], 0, 0, 0);
                }
            }
        }
        cur ^= 1;
    }

    const bool cond = (*gsum) > 4096.f;  // mean(gate) > 0.5
#pragma unroll
    for (int m = 0; m < 4; m++) {
        int rbase = m0 + waver * 64 + m * 16 + lk * 4;
        float corr[4];
#pragma unroll
        for (int j = 0; j < 4; j++) corr[j] = cond ? sdot[rbase + j] : 0.f;
#pragma unroll
        for (int n = 0; n < 2; n++) {
            int c = c0 + wavec * 32 + n * 16 + lrow;
            float br = bih[c], bz = bih[E + c], bn = bih[2 * E + c];
            float hr = bhh[c], hz = bhh[E + c], hn = bhh[2 * E + c];
#pragma unroll
            for (int j = 0; j < 4; j++) {
                float ir = acc[m][0 + n][j] + br + corr[j];
                float iz = acc[m][2 + n][j] + bz + corr[j];
                float inn = acc[m][4 + n][j] + bn + corr[j];
                float r = sigmoidf_(ir + hr);
                float z = sigmoidf_(iz + hz);
                float nn = tanhf_(inn + r * hn);
                float h = (1.f - z) * nn;
                float o = h + h2f(sig[(size_t)(rbase + j) * E + c]);
                if (curf_out) curf_out[(size_t)(rbase + j) * E + c] = o;
                if (curb_out) curb_out[(size_t)(rbase + j) * E + c] = f2h(o);
            }
        }
    }
}

// ---------------------------------------------------------------------------
extern "C" void kernel_launch(void* const* d_in, const int* in_sizes, int n_in,
                              void* d_out, int out_size, void* d_ws, size_t ws_size,
                              hipStream_t stream) {
    const float* x   = (const float*)d_in[0];
    const float* Wih = (const float*)d_in[1];
    // d_in[2] = W_hh : unused (h_prev == 0)
    const float* bih = (const float*)d_in[3];
    const float* bhh = (const float*)d_in[4];
    const float* W1  = (const float*)d_in[5];
    const float* b1  = (const float*)d_in[6];
    const float* W2  = (const float*)d_in[7];
    const float* b2  = (const float*)d_in[8];
    const float* Wg  = (const float*)d_in[9];
    const float* bg  = (const float*)d_in[10];
    float* out = (float*)d_out;

    char* w = (char*)d_ws;
    u16* Wihb  = (u16*)w;  w += (size_t)3 * 3072 * 1024 * 2;   // 18.9 MB
    u16* W1b   = (u16*)w;  w += (size_t)3 * 512 * 1024 * 2;    //  3.1 MB
    u16* W2b   = (u16*)w;  w += (size_t)3 * 1024 * 512 * 2;    //  3.1 MB
    u16* curbA = (u16*)w;  w += (size_t)BSZ * ESZ * 2;         // 16.8 MB
    u16* curbB = (u16*)w;  w += (size_t)BSZ * ESZ * 2;         // 16.8 MB
    u16* Amat  = (u16*)w;  w += (size_t)BSZ * 512 * 2;         //  8.4 MB
    u16* sigb  = (u16*)w;  w += (size_t)BSZ * ESZ * 2;         // 16.8 MB
    float* colsum = (float*)w;  w += 4096;                     // 1024 f32
    float* gsum   = (float*)w;  w += 256;                      // 1 f32 (+pad)
    float* sdot   = (float*)w;  w += (size_t)BSZ * 4;          // 32 KB

    // f16 conversions (every call — no persistent state allowed)
    {
        int n4 = N4_WIH + N4_W1 + N4_W2 + N4_X;
        cvt_all_kernel<<<dim3((n4 + 255) / 256), 256, 0, stream>>>(
            Wih, W1, W2, x, Wihb, W1b, W2b, curbA);
    }

    u16* cin = curbA;
    u16* cout = curbB;
    for (int l = 0; l < 3; l++) {
        hipMemsetAsync(colsum, 0, 4096 + 4, stream);  // colsum + gsum
        // sig = tanh(relu(cur@W1^T+b1)@W2^T+b2) (f16), plus fp32 column sums
        gemm_act_kernel<0><<<dim3(512 / 128, BSZ / 128), 256, 0, stream>>>(
            cin, W1b + (size_t)l * 512 * 1024, b1 + l * 512, Amat, nullptr, 512, 1024);
        gemm_act_kernel<1><<<dim3(1024 / 128, BSZ / 128), 256, 0, stream>>>(
            Amat, W2b + (size_t)l * 1024 * 512, b2 + l * 1024, sigb, colsum, 1024, 512);
        // gate mean (-> cond) and rank-1 row dots (fp32 accumulate, f16 cur)
        gate_kernel<<<dim3(BSZ / 4), 256, 0, stream>>>(
            cin, Wg + l * 1024, bg + l, colsum, gsum, sdot);
        // fused GRU: gi = cur@W_ih^T (+rank-1), elementwise cell, += sig
        gemm_gru_kernel<<<dim3(16, BSZ / 128), 256, 0, stream>>>(
            cin, Wihb + (size_t)l * 3072 * 1024, bih + l * 3072, bhh + l * 3072,
            sigb, sdot, gsum, (l == 2) ? out : nullptr, (l < 2) ? cout : nullptr);
        u16* tmp = cin; cin = cout; cout = tmp;
    }
}

// Round 5
// 582.334 us; speedup vs baseline: 1.0225x; 1.0225x over previous
//
#include <hip/hip_runtime.h>
#include <cstdint>
#include <cstddef>

// ---------------------------------------------------------------------------
// SelfModifyingRecurrent: B=8192, E=1024, L=3
//   * h_prev stays ZERO -> gh = b_hh (const), no W_hh GEMM
//   * weight modification is rank-1 -> gi += cond * 0.01*dot(cur, mean_sig)
// f16 MFMA (16x16x32) fp32-accum. LDS XOR-swizzle via pre-swizzled global
// source + swizzled ds_read. Both GEMM families use the 2-phase double-
// buffered K-loop (STAGE(next) before compute(cur), ONE barrier per step).
// R4 counters: gru 103->81us from dbuf; act kernels now dominate (~90us/layer,
// act0 at 1 block/CU single-buffered) -> this round rebuilds act with
// 128x64 tiles + dbuf + XCD-chunked remap.
// ---------------------------------------------------------------------------

#define BSZ 8192
#define ESZ 1024

typedef _Float16 f16x8 __attribute__((ext_vector_type(8)));
typedef float    f32x4 __attribute__((ext_vector_type(4)));
typedef unsigned short u16;
typedef u16 u16x4 __attribute__((ext_vector_type(4)));

__device__ __forceinline__ u16 f2h(float f) {
    _Float16 h = (_Float16)f;
    return __builtin_bit_cast(u16, h);
}
__device__ __forceinline__ float h2f(u16 h) {
    return (float)__builtin_bit_cast(_Float16, h);
}

__device__ __forceinline__ void gload16(const void* g, void* l) {
    __builtin_amdgcn_global_load_lds((const __attribute__((address_space(1))) void*)g,
                                     (__attribute__((address_space(3))) void*)l,
                                     16, 0, 0);
}

// swizzled LDS u16 index: row-stride 64 u16 (128B), chunk = 8-u16 (16B) slot 0..7
__device__ __forceinline__ int swzi(int row, int chunk) {
    return (row << 6) + (((chunk ^ row) & 7) << 3);
}

__device__ __forceinline__ float sigmoidf_(float x) {
    return 1.f / (1.f + __expf(-x));
}
__device__ __forceinline__ float tanhf_(float x) {
    float cx = fminf(fmaxf(x, -15.f), 15.f);
    float e = __expf(2.f * cx);
    return (e - 1.f) / (e + 1.f);
}

// ---------------------------------------------------------------------------
// fused fp32 -> f16 conversion for Wih, W1, W2, x (one launch)
// ---------------------------------------------------------------------------
#define N4_WIH (3 * 3072 * 1024 / 4)
#define N4_W1  (3 * 512 * 1024 / 4)
#define N4_W2  (3 * 1024 * 512 / 4)
#define N4_X   (BSZ * ESZ / 4)

__global__ void cvt_all_kernel(const float* __restrict__ Wih, const float* __restrict__ W1,
                               const float* __restrict__ W2, const float* __restrict__ x,
                               u16* __restrict__ oWih, u16* __restrict__ oW1,
                               u16* __restrict__ oW2, u16* __restrict__ ox) {
    int i = blockIdx.x * 256 + threadIdx.x;
    const float* in;
    u16* out;
    if (i < N4_WIH) { in = Wih; out = oWih; }
    else if (i < N4_WIH + N4_W1) { i -= N4_WIH; in = W1; out = oW1; }
    else if (i < N4_WIH + N4_W1 + N4_W2) { i -= N4_WIH + N4_W1; in = W2; out = oW2; }
    else { i -= N4_WIH + N4_W1 + N4_W2; if (i >= N4_X) return; in = x; out = ox; }
    f32x4 v = ((const f32x4*)in)[i];
    u16x4 o;
    o.x = f2h(v.x); o.y = f2h(v.y); o.z = f2h(v.z); o.w = f2h(v.w);
    ((u16x4*)out)[i] = o;
}

// ---------------------------------------------------------------------------
// Gate kernel (reads f16 cur): per row r:
//   gate_r = sigmoid(dot(cur_r, Wg) + bg)       -> atomic sum into gsum
//   sdot_r = dot(cur_r, colsum_sig)*(0.01/B)
// One wave per row, 4 rows per block; fp32 accumulate.
// ---------------------------------------------------------------------------
__global__ void gate_kernel(const u16* __restrict__ cur, const float* __restrict__ Wg,
                            const float* __restrict__ bg, const float* __restrict__ colsum,
                            float* __restrict__ gsum, float* __restrict__ sdot) {
    const int wid = threadIdx.x >> 6, lane = threadIdx.x & 63;
    const int row = blockIdx.x * 4 + wid;
    const u16* cr = cur + (size_t)row * ESZ;
    float pg = 0.f, pm = 0.f;
#pragma unroll
    for (int h = 0; h < 2; h++) {
        int base = lane * 16 + h * 8;
        f16x8 cv = *(const f16x8*)(cr + base);
#pragma unroll
        for (int q = 0; q < 2; q++) {
            f32x4 wv = *(const f32x4*)(Wg + base + q * 4);
            f32x4 mv = *(const f32x4*)(colsum + base + q * 4);
#pragma unroll
            for (int e = 0; e < 4; e++) {
                float c = (float)cv[q * 4 + e];
                pg += c * wv[e];
                pm += c * mv[e];
            }
        }
    }
#pragma unroll
    for (int s = 32; s >= 1; s >>= 1) {
        pg += __shfl_xor(pg, s);
        pm += __shfl_xor(pm, s);
    }
    __shared__ float gp[4];
    if (lane == 0) {
        gp[wid] = sigmoidf_(pg + bg[0]);
        sdot[row] = pm * (0.01f / 8192.f);
    }
    __syncthreads();
    if (threadIdx.x == 0) atomicAdd(gsum, gp[0] + gp[1] + gp[2] + gp[3]);
}

// ---------------------------------------------------------------------------
// Act GEMM: C[M,N] = act(A[M,K] @ W[N,K]^T + bias), 128x64 tile, BK=64,
// 2-phase double-buffered, 4 waves (2x2: 64x32 wave tile), swizzled staging.
// ACT=0: relu -> f16 out.  ACT=1: tanh -> f16 out + fp32 column-sum atomics.
// Grid is 1-D; XCD-chunked remap (grid%8==0) keeps each XCD's A panels
// (~2MB) + W (1MB) L2-resident. LDS 48KB -> 3 blocks/CU possible.
// ---------------------------------------------------------------------------
template <int ACT>
__global__ void __launch_bounds__(256, 3) gemm_act_kernel(
    const u16* __restrict__ A, const u16* __restrict__ W,
    const float* __restrict__ bias, u16* __restrict__ outp,
    float* __restrict__ colsum, int N, int K, int nshift) {
    __shared__ u16 lA[2][128 * 64];
    __shared__ u16 lB[2][64 * 64];
    const int t = threadIdx.x;
    const int chunk = gridDim.x >> 3;
    const int o = blockIdx.x;
    const int tl = (o & 7) * chunk + (o >> 3);          // XCD-chunked, bijective
    const int m0 = (tl >> nshift) * 128;
    const int n0 = (tl & ((1 << nshift) - 1)) * 64;
    const int wid = t >> 6, lane = t & 63;
    const int waver = wid >> 1, wavec = wid & 1;
    const int lrow = lane & 15, lk = lane >> 4;

    f32x4 acc[4][2] = {};

    auto STAGE = [&](int buf, int k0) {
#pragma unroll
        for (int i = 0; i < 4; i++) {
            int eo = i * 2048 + t * 8;
            int r = eo >> 6;
            int gc = (((eo >> 3) ^ r) & 7) << 3;
            gload16(A + (size_t)(m0 + r) * K + k0 + gc, &lA[buf][eo]);
        }
#pragma unroll
        for (int i = 0; i < 2; i++) {
            int eo = i * 2048 + t * 8;
            int r = eo >> 6;
            int gc = (((eo >> 3) ^ r) & 7) << 3;
            gload16(W + (size_t)(n0 + r) * K + k0 + gc, &lB[buf][eo]);
        }
    };

    STAGE(0, 0);
    const int nk = K >> 6;
    int cur = 0;
    for (int kt = 0; kt < nk; ++kt) {
        __syncthreads();
        if (kt + 1 < nk) STAGE(cur ^ 1, (kt + 1) * 64);
#pragma unroll
        for (int kk = 0; kk < 2; kk++) {
            f16x8 af[4], bf[2];
#pragma unroll
            for (int m = 0; m < 4; m++)
                af[m] = *(const f16x8*)&lA[cur][swzi(waver * 64 + m * 16 + lrow, kk * 4 + lk)];
#pragma unroll
            for (int n = 0; n < 2; n++)
                bf[n] = *(const f16x8*)&lB[cur][swzi(wavec * 32 + n * 16 + lrow, kk * 4 + lk)];
#pragma unroll
            for (int m = 0; m < 4; m++)
#pragma unroll
                for (int n = 0; n < 2; n++)
                    acc[m][n] = __builtin_amdgcn_mfma_f32_16x16x32_f16(af[m], bf[n], acc[m][n], 0, 0, 0);
        }
        cur ^= 1;
    }

#pragma unroll
    for (int n = 0; n < 2; n++) {
        int c = n0 + wavec * 32 + n * 16 + lrow;
        float bv = bias[c];
        float cs = 0.f;
#pragma unroll
        for (int m = 0; m < 4; m++) {
            int rbase = m0 + waver * 64 + m * 16 + lk * 4;
#pragma unroll
            for (int j = 0; j < 4; j++) {
                float v = acc[m][n][j] + bv;
                if (ACT == 0) {
                    v = v > 0.f ? v : 0.f;
                    outp[(size_t)(rbase + j) * N + c] = f2h(v);
                } else {
                    float tv = tanhf_(v);
                    outp[(size_t)(rbase + j) * N + c] = f2h(tv);
                    cs += tv;
                }
            }
        }
        if (ACT == 1) {
            cs += __shfl_xor(cs, 16);
            cs += __shfl_xor(cs, 32);
            if (lane < 16) atomicAdd(&colsum[c], cs);
        }
    }
}

// ---------------------------------------------------------------------------
// Fused GEMM3 + GRU epilogue, 2-phase double-buffered (unchanged from R4).
// 128 rows x 64 sig-cols x 3 gate groups per block.
//   i_* = gi_* + b_ih[*] + cond*sdot[row]
//   r = sig(i_r + b_hh_r); z = sig(i_z + b_hh_z); n = tanh(i_n + r*b_hh_n)
//   cur_out = (1-z)*n + sig_mlp[row,c]
// ---------------------------------------------------------------------------
__global__ void __launch_bounds__(256, 2) gemm_gru_kernel(
    const u16* __restrict__ Ab, const u16* __restrict__ Wb,
    const float* __restrict__ bih, const float* __restrict__ bhh,
    const u16* __restrict__ sig, const float* __restrict__ sdot,
    const float* __restrict__ gsum, float* __restrict__ curf_out,
    u16* __restrict__ curb_out) {
    __shared__ u16 lA[2][128 * 64];
    __shared__ u16 lB[2][3][64 * 64];
    const int t = threadIdx.x;
    // XCD-bijective remap: each XCD owns 2 col-blocks x all 64 row-panels so
    // its W_ih working set (~786 KB) stays L2-resident.
    const int hw = blockIdx.y * 16 + blockIdx.x;
    const int xcd = hw & 7, idx = hw >> 3;
    const int m0 = (idx >> 1) * 128, c0 = ((xcd << 1) | (idx & 1)) * 64;
    const int wid = t >> 6, lane = t & 63;
    const int waver = wid >> 1, wavec = wid & 1;
    const int lrow = lane & 15, lk = lane >> 4;
    const int K = ESZ, E = ESZ;

    const int eoA = t * 8;
    f32x4 acc[4][6] = {};

    auto STAGE = [&](int buf, int k0) {
#pragma unroll
        for (int i = 0; i < 4; i++) {
            int eo = i * 2048 + eoA;
            int r = eo >> 6;
            int gc = (((eo >> 3) ^ r) & 7) << 3;
            gload16(Ab + (size_t)(m0 + r) * K + k0 + gc, &lA[buf][eo]);
        }
#pragma unroll
        for (int g = 0; g < 3; g++)
#pragma unroll
            for (int i = 0; i < 2; i++) {
                int eo = i * 2048 + eoA;
                int r = eo >> 6;
                int gc = (((eo >> 3) ^ r) & 7) << 3;
                gload16(Wb + (size_t)(g * 1024 + c0 + r) * K + k0 + gc, &lB[buf][g][eo]);
            }
    };

    STAGE(0, 0);
    int cur = 0;
    for (int kt = 0; kt < 16; ++kt) {
        __syncthreads();
        if (kt < 15) STAGE(cur ^ 1, (kt + 1) * 64);
#pragma unroll
        for (int kk = 0; kk < 2; kk++) {
            f16x8 af[4];
#pragma unroll
            for (int m = 0; m < 4; m++)
                af[m] = *(const f16x8*)&lA[cur][swzi(waver * 64 + m * 16 + lrow, kk * 4 + lk)];
#pragma unroll
            for (int g = 0; g < 3; g++) {
#pragma unroll
                for (int n = 0; n < 2; n++) {
                    f16x8 bf = *(const f16x8*)&lB[cur][g][swzi(wavec * 32 + n * 16 + lrow, kk * 4 + lk)];
#pragma unroll
                    for (int m = 0; m < 4; m++)
                        acc[m][g * 2 + n] =
                            __builtin_amdgcn_mfma_f32_16x16x32_f16(af[m], bf, acc[m][g * 2 + n], 0, 0, 0);
                }
            }
        }
        cur ^= 1;
    }

    const bool cond = (*gsum) > 4096.f;  // mean(gate) > 0.5
#pragma unroll
    for (int m = 0; m < 4; m++) {
        int rbase = m0 + waver * 64 + m * 16 + lk * 4;
        float corr[4];
#pragma unroll
        for (int j = 0; j < 4; j++) corr[j] = cond ? sdot[rbase + j] : 0.f;
#pragma unroll
        for (int n = 0; n < 2; n++) {
            int c = c0 + wavec * 32 + n * 16 + lrow;
            float br = bih[c], bz = bih[E + c], bn = bih[2 * E + c];
            float hr = bhh[c], hz = bhh[E + c], hn = bhh[2 * E + c];
#pragma unroll
            for (int j = 0; j < 4; j++) {
                float ir = acc[m][0 + n][j] + br + corr[j];
                float iz = acc[m][2 + n][j] + bz + corr[j];
                float inn = acc[m][4 + n][j] + bn + corr[j];
                float r = sigmoidf_(ir + hr);
                float z = sigmoidf_(iz + hz);
                float nn = tanhf_(inn + r * hn);
                float h = (1.f - z) * nn;
                float o = h + h2f(sig[(size_t)(rbase + j) * E + c]);
                if (curf_out) curf_out[(size_t)(rbase + j) * E + c] = o;
                if (curb_out) curb_out[(size_t)(rbase + j) * E + c] = f2h(o);
            }
        }
    }
}

// ---------------------------------------------------------------------------
extern "C" void kernel_launch(void* const* d_in, const int* in_sizes, int n_in,
                              void* d_out, int out_size, void* d_ws, size_t ws_size,
                              hipStream_t stream) {
    const float* x   = (const float*)d_in[0];
    const float* Wih = (const float*)d_in[1];
    // d_in[2] = W_hh : unused (h_prev == 0)
    const float* bih = (const float*)d_in[3];
    const float* bhh = (const float*)d_in[4];
    const float* W1  = (const float*)d_in[5];
    const float* b1  = (const float*)d_in[6];
    const float* W2  = (const float*)d_in[7];
    const float* b2  = (const float*)d_in[8];
    const float* Wg  = (const float*)d_in[9];
    const float* bg  = (const float*)d_in[10];
    float* out = (float*)d_out;

    char* w = (char*)d_ws;
    u16* Wihb  = (u16*)w;  w += (size_t)3 * 3072 * 1024 * 2;   // 18.9 MB
    u16* W1b   = (u16*)w;  w += (size_t)3 * 512 * 1024 * 2;    //  3.1 MB
    u16* W2b   = (u16*)w;  w += (size_t)3 * 1024 * 512 * 2;    //  3.1 MB
    u16* curbA = (u16*)w;  w += (size_t)BSZ * ESZ * 2;         // 16.8 MB
    u16* curbB = (u16*)w;  w += (size_t)BSZ * ESZ * 2;         // 16.8 MB
    u16* Amat  = (u16*)w;  w += (size_t)BSZ * 512 * 2;         //  8.4 MB
    u16* sigb  = (u16*)w;  w += (size_t)BSZ * ESZ * 2;         // 16.8 MB
    float* colsum = (float*)w;  w += 4096;                     // 1024 f32
    float* gsum   = (float*)w;  w += 256;                      // 1 f32 (+pad)
    float* sdot   = (float*)w;  w += (size_t)BSZ * 4;          // 32 KB

    // f16 conversions (every call — no persistent state allowed)
    {
        int n4 = N4_WIH + N4_W1 + N4_W2 + N4_X;
        cvt_all_kernel<<<dim3((n4 + 255) / 256), 256, 0, stream>>>(
            Wih, W1, W2, x, Wihb, W1b, W2b, curbA);
    }

    u16* cin = curbA;
    u16* cout = curbB;
    for (int l = 0; l < 3; l++) {
        hipMemsetAsync(colsum, 0, 4096 + 4, stream);  // colsum + gsum
        // sig = tanh(relu(cur@W1^T+b1)@W2^T+b2) (f16), plus fp32 column sums
        gemm_act_kernel<0><<<dim3(512), 256, 0, stream>>>(
            cin, W1b + (size_t)l * 512 * 1024, b1 + l * 512, Amat, nullptr, 512, 1024, 3);
        gemm_act_kernel<1><<<dim3(1024), 256, 0, stream>>>(
            Amat, W2b + (size_t)l * 1024 * 512, b2 + l * 1024, sigb, colsum, 1024, 512, 4);
        // gate mean (-> cond) and rank-1 row dots (fp32 accumulate, f16 cur)
        gate_kernel<<<dim3(BSZ / 4), 256, 0, stream>>>(
            cin, Wg + l * 1024, bg + l, colsum, gsum, sdot);
        // fused GRU: gi = cur@W_ih^T (+rank-1), elementwise cell, += sig
        gemm_gru_kernel<<<dim3(16, BSZ / 128), 256, 0, stream>>>(
            cin, Wihb + (size_t)l * 3072 * 1024, bih + l * 3072, bhh + l * 3072,
            sigb, sdot, gsum, (l == 2) ? out : nullptr, (l < 2) ? cout : nullptr);
        u16* tmp = cin; cin = cout; cout = tmp;
    }
}

// Round 7
// 581.029 us; speedup vs baseline: 1.0248x; 1.0022x over previous
//
#include <hip/hip_runtime.h>
#include <cstdint>
#include <cstddef>

// ---------------------------------------------------------------------------
// SelfModifyingRecurrent: B=8192, E=1024, L=3
//   * h_prev stays ZERO -> gh = b_hh (const), no W_hh GEMM
//   * weight modification is rank-1 -> gi += cond * 0.01*dot(cur, mean_sig)
// R5 analysis: gemm_gru bound by L2-miss traffic (col-chunk remap streamed
// full A through every XCD's L2; 128-row tiles doubled B staging). This round:
// unified gemm_fused<NG,EPI>: BM=256 (8 waves, 512 thr), 2-phase dbuf,
// XCD ROW-chunk remap (A panel L2-resident/XCD) with column-outer order
// (W chunk reused across the XCD's 4 panels).
// ---------------------------------------------------------------------------

#define BSZ 8192
#define ESZ 1024

typedef _Float16 f16x8 __attribute__((ext_vector_type(8)));
typedef float    f32x4 __attribute__((ext_vector_type(4)));
typedef unsigned short u16;
typedef u16 u16x4 __attribute__((ext_vector_type(4)));

__device__ __forceinline__ u16 f2h(float f) {
    _Float16 h = (_Float16)f;
    return __builtin_bit_cast(u16, h);
}
__device__ __forceinline__ float h2f(u16 h) {
    return (float)__builtin_bit_cast(_Float16, h);
}

__device__ __forceinline__ void gload16(const void* g, void* l) {
    __builtin_amdgcn_global_load_lds((const __attribute__((address_space(1))) void*)g,
                                     (__attribute__((address_space(3))) void*)l,
                                     16, 0, 0);
}

// swizzled LDS u16 index: row-stride 64 u16 (128B), chunk = 8-u16 (16B) slot 0..7
__device__ __forceinline__ int swzi(int row, int chunk) {
    return (row << 6) + (((chunk ^ row) & 7) << 3);
}

__device__ __forceinline__ float sigmoidf_(float x) {
    return 1.f / (1.f + __expf(-x));
}
__device__ __forceinline__ float tanhf_(float x) {
    float cx = fminf(fmaxf(x, -15.f), 15.f);
    float e = __expf(2.f * cx);
    return (e - 1.f) / (e + 1.f);
}

// ---------------------------------------------------------------------------
// fused fp32 -> f16 conversion for Wih, W1, W2, x (one launch)
// ---------------------------------------------------------------------------
#define N4_WIH (3 * 3072 * 1024 / 4)
#define N4_W1  (3 * 512 * 1024 / 4)
#define N4_W2  (3 * 1024 * 512 / 4)
#define N4_X   (BSZ * ESZ / 4)

__global__ void cvt_all_kernel(const float* __restrict__ Wih, const float* __restrict__ W1,
                               const float* __restrict__ W2, const float* __restrict__ x,
                               u16* __restrict__ oWih, u16* __restrict__ oW1,
                               u16* __restrict__ oW2, u16* __restrict__ ox) {
    int i = blockIdx.x * 256 + threadIdx.x;
    const float* in;
    u16* out;
    if (i < N4_WIH) { in = Wih; out = oWih; }
    else if (i < N4_WIH + N4_W1) { i -= N4_WIH; in = W1; out = oW1; }
    else if (i < N4_WIH + N4_W1 + N4_W2) { i -= N4_WIH + N4_W1; in = W2; out = oW2; }
    else { i -= N4_WIH + N4_W1 + N4_W2; if (i >= N4_X) return; in = x; out = ox; }
    f32x4 v = ((const f32x4*)in)[i];
    u16x4 o;
    o.x = f2h(v.x); o.y = f2h(v.y); o.z = f2h(v.z); o.w = f2h(v.w);
    ((u16x4*)out)[i] = o;
}

// ---------------------------------------------------------------------------
// Gate kernel (reads f16 cur): per row r:
//   gate_r = sigmoid(dot(cur_r, Wg) + bg)       -> atomic sum into gsum
//   sdot_r = dot(cur_r, colsum_sig)*(0.01/B)
// One wave per row, 4 rows per block; fp32 accumulate.
// ---------------------------------------------------------------------------
__global__ void gate_kernel(const u16* __restrict__ cur, const float* __restrict__ Wg,
                            const float* __restrict__ bg, const float* __restrict__ colsum,
                            float* __restrict__ gsum, float* __restrict__ sdot) {
    const int wid = threadIdx.x >> 6, lane = threadIdx.x & 63;
    const int row = blockIdx.x * 4 + wid;
    const u16* cr = cur + (size_t)row * ESZ;
    float pg = 0.f, pm = 0.f;
#pragma unroll
    for (int h = 0; h < 2; h++) {
        int base = lane * 16 + h * 8;
        f16x8 cv = *(const f16x8*)(cr + base);
#pragma unroll
        for (int q = 0; q < 2; q++) {
            f32x4 wv = *(const f32x4*)(Wg + base + q * 4);
            f32x4 mv = *(const f32x4*)(colsum + base + q * 4);
#pragma unroll
            for (int e = 0; e < 4; e++) {
                float c = (float)cv[q * 4 + e];
                pg += c * wv[e];
                pm += c * mv[e];
            }
        }
    }
#pragma unroll
    for (int s = 32; s >= 1; s >>= 1) {
        pg += __shfl_xor(pg, s);
        pm += __shfl_xor(pm, s);
    }
    __shared__ float gp[4];
    if (lane == 0) {
        gp[wid] = sigmoidf_(pg + bg[0]);
        sdot[row] = pm * (0.01f / 8192.f);
    }
    __syncthreads();
    if (threadIdx.x == 0) atomicAdd(gsum, gp[0] + gp[1] + gp[2] + gp[3]);
}

// ---------------------------------------------------------------------------
// Unified fused GEMM. C-tile = 256 rows x (NG groups x 64 cols), BK=64,
// 8 waves (512 thr) as 4M x 2N (per-wave 64 rows x 32 cols x NG groups).
// 2-phase double-buffered K-loop (STAGE(next) after the single barrier,
// compute(cur) underneath). XOR-swizzled staging (pre-swizzled global src).
//
// Grid: 32*NC blocks, 1-D. XCD row-chunk remap: xcd = bid%8 owns 4 contiguous
// 256-row panels (A chunk 2.1MB -> L2-resident); within an XCD, columns are
// OUTER (q>>2) and panels INNER (q&3) so the W column chunk is reused by all
// 4 panels before moving on.
//
// EPI=0: relu -> f16 out (N = NC*64)
// EPI=1: tanh -> f16 out + fp32 column-sum atomics
// EPI=2: GRU cell: NG=3 gate groups, h_prev=0, rank-1 corr, += sig
// ---------------------------------------------------------------------------
template <int NG, int EPI>
__global__ void __launch_bounds__(512, 2) gemm_fused_kernel(
    const u16* __restrict__ A, const u16* __restrict__ W,
    const float* __restrict__ bias, const float* __restrict__ bhh,
    const u16* __restrict__ sig, const float* __restrict__ sdot,
    const float* __restrict__ gsum, u16* __restrict__ outp,
    float* __restrict__ curf_out, float* __restrict__ colsum,
    int K, int NC) {
    __shared__ u16 lA[2][256 * 64];
    __shared__ u16 lB[2][NG][64 * 64];
    const int t = threadIdx.x;
    const int xcd = blockIdx.x & 7, q = blockIdx.x >> 3;
    const int m0 = (xcd * 4 + (q & 3)) * 256;   // 4 contiguous panels per XCD
    const int c0 = (q >> 2) * 64;               // column-outer within XCD
    const int wid = t >> 6, lane = t & 63;
    const int waver = wid >> 1, wavec = wid & 1;
    const int lrow = lane & 15, lk = lane >> 4;
    const int E = ESZ;

    f32x4 acc[4][2 * NG] = {};

    auto STAGE = [&](int buf, int k0) {
#pragma unroll
        for (int i = 0; i < 4; i++) {
            int eo = i * 4096 + t * 8;
            int r = eo >> 6;
            int gc = (((eo >> 3) ^ r) & 7) << 3;
            gload16(A + (size_t)(m0 + r) * K + k0 + gc, &lA[buf][eo]);
        }
#pragma unroll
        for (int g = 0; g < NG; g++) {
            int eo = t * 8;
            int r = eo >> 6;
            int gc = (((eo >> 3) ^ r) & 7) << 3;
            gload16(W + (size_t)(g * 1024 + c0 + r) * K + k0 + gc, &lB[buf][g][eo]);
        }
    };

    STAGE(0, 0);
    const int nk = K >> 6;
    int cur = 0;
    for (int kt = 0; kt < nk; ++kt) {
        __syncthreads();  // wave-local vmcnt(0): buf[cur] staged; lgkm: reads done
        if (kt + 1 < nk) STAGE(cur ^ 1, (kt + 1) * 64);
#pragma unroll
        for (int kk = 0; kk < 2; kk++) {
            f16x8 af[4];
#pragma unroll
            for (int m = 0; m < 4; m++)
                af[m] = *(const f16x8*)&lA[cur][swzi(waver * 64 + m * 16 + lrow, kk * 4 + lk)];
#pragma unroll
            for (int g = 0; g < NG; g++) {
#pragma unroll
                for (int n = 0; n < 2; n++) {
                    f16x8 bf = *(const f16x8*)&lB[cur][g][swzi(wavec * 32 + n * 16 + lrow, kk * 4 + lk)];
#pragma unroll
                    for (int m = 0; m < 4; m++)
                        acc[m][g * 2 + n] =
                            __builtin_amdgcn_mfma_f32_16x16x32_f16(af[m], bf, acc[m][g * 2 + n], 0, 0, 0);
                }
            }
        }
        cur ^= 1;
    }

    if (EPI == 2) {
        const bool cond = (*gsum) > 4096.f;  // mean(gate) > 0.5
#pragma unroll
        for (int m = 0; m < 4; m++) {
            int rbase = m0 + waver * 64 + m * 16 + lk * 4;
            float corr[4];
#pragma unroll
            for (int j = 0; j < 4; j++) corr[j] = cond ? sdot[rbase + j] : 0.f;
#pragma unroll
            for (int n = 0; n < 2; n++) {
                int c = c0 + wavec * 32 + n * 16 + lrow;
                float br = bias[c], bz = bias[E + c], bn = bias[2 * E + c];
                float hr = bhh[c], hz = bhh[E + c], hn = bhh[2 * E + c];
#pragma unroll
                for (int j = 0; j < 4; j++) {
                    float ir = acc[m][0 + n][j] + br + corr[j];
                    float iz = acc[m][2 + n][j] + bz + corr[j];
                    float inn = acc[m][4 + n][j] + bn + corr[j];
                    float r = sigmoidf_(ir + hr);
                    float z = sigmoidf_(iz + hz);
                    float nn = tanhf_(inn + r * hn);
                    float h = (1.f - z) * nn;
                    float o = h + h2f(sig[(size_t)(rbase + j) * E + c]);
                    if (curf_out) curf_out[(size_t)(rbase + j) * E + c] = o;
                    if (outp) outp[(size_t)(rbase + j) * E + c] = f2h(o);
                }
            }
        }
    } else {
        const int N = NC << 6;
#pragma unroll
        for (int n = 0; n < 2; n++) {
            int c = c0 + wavec * 32 + n * 16 + lrow;
            float bv = bias[c];
            float cs = 0.f;
#pragma unroll
            for (int m = 0; m < 4; m++) {
                int rbase = m0 + waver * 64 + m * 16 + lk * 4;
#pragma unroll
                for (int j = 0; j < 4; j++) {
                    float v = acc[m][n][j] + bv;
                    if (EPI == 0) {
                        v = v > 0.f ? v : 0.f;
                        outp[(size_t)(rbase + j) * N + c] = f2h(v);
                    } else {
                        float tv = tanhf_(v);
                        outp[(size_t)(rbase + j) * N + c] = f2h(tv);
                        cs += tv;
                    }
                }
            }
            if (EPI == 1) {
                cs += __shfl_xor(cs, 16);
                cs += __shfl_xor(cs, 32);
                if (lane < 16) atomicAdd(&colsum[c], cs);
            }
        }
    }
}

// ---------------------------------------------------------------------------
extern "C" void kernel_launch(void* const* d_in, const int* in_sizes, int n_in,
                              void* d_out, int out_size, void* d_ws, size_t ws_size,
                              hipStream_t stream) {
    const float* x   = (const float*)d_in[0];
    const float* Wih = (const float*)d_in[1];
    // d_in[2] = W_hh : unused (h_prev == 0)
    const float* bih = (const float*)d_in[3];
    const float* bhh = (const float*)d_in[4];
    const float* W1  = (const float*)d_in[5];
    const float* b1  = (const float*)d_in[6];
    const float* W2  = (const float*)d_in[7];
    const float* b2  = (const float*)d_in[8];
    const float* Wg  = (const float*)d_in[9];
    const float* bg  = (const float*)d_in[10];
    float* out = (float*)d_out;

    char* w = (char*)d_ws;
    u16* Wihb  = (u16*)w;  w += (size_t)3 * 3072 * 1024 * 2;   // 18.9 MB
    u16* W1b   = (u16*)w;  w += (size_t)3 * 512 * 1024 * 2;    //  3.1 MB
    u16* W2b   = (u16*)w;  w += (size_t)3 * 1024 * 512 * 2;    //  3.1 MB
    u16* curbA = (u16*)w;  w += (size_t)BSZ * ESZ * 2;         // 16.8 MB
    u16* curbB = (u16*)w;  w += (size_t)BSZ * ESZ * 2;         // 16.8 MB
    u16* Amat  = (u16*)w;  w += (size_t)BSZ * 512 * 2;         //  8.4 MB
    u16* sigb  = (u16*)w;  w += (size_t)BSZ * ESZ * 2;         // 16.8 MB
    float* colsum = (float*)w;  w += 4096;                     // 1024 f32
    float* gsum   = (float*)w;  w += 256;                      // 1 f32 (+pad)
    float* sdot   = (float*)w;  w += (size_t)BSZ * 4;          // 32 KB

    // f16 conversions (every call — no persistent state allowed)
    {
        int n4 = N4_WIH + N4_W1 + N4_W2 + N4_X;
        cvt_all_kernel<<<dim3((n4 + 255) / 256), 256, 0, stream>>>(
            Wih, W1, W2, x, Wihb, W1b, W2b, curbA);
    }

    u16* cin = curbA;
    u16* cout = curbB;
    for (int l = 0; l < 3; l++) {
        hipMemsetAsync(colsum, 0, 4096 + 4, stream);  // colsum + gsum
        // act0: Amat = relu(cur@W1^T + b1)   [M=8192, N=512, K=1024]
        gemm_fused_kernel<1, 0><<<dim3(32 * 8), 512, 0, stream>>>(
            cin, W1b + (size_t)l * 512 * 1024, b1 + l * 512, nullptr,
            nullptr, nullptr, nullptr, Amat, nullptr, nullptr, 1024, 8);
        // act1: sig = tanh(Amat@W2^T + b2) (f16) + fp32 column sums
        gemm_fused_kernel<1, 1><<<dim3(32 * 16), 512, 0, stream>>>(
            Amat, W2b + (size_t)l * 1024 * 512, b2 + l * 1024, nullptr,
            nullptr, nullptr, nullptr, sigb, nullptr, colsum, 512, 16);
        // gate mean (-> cond) and rank-1 row dots (fp32 accumulate, f16 cur)
        gate_kernel<<<dim3(BSZ / 4), 256, 0, stream>>>(
            cin, Wg + l * 1024, bg + l, colsum, gsum, sdot);
        // fused GRU: gi = cur@W_ih^T (+rank-1), elementwise cell, += sig
        gemm_fused_kernel<3, 2><<<dim3(32 * 16), 512, 0, stream>>>(
            cin, Wihb + (size_t)l * 3072 * 1024, bih + l * 3072, bhh + l * 3072,
            sigb, sdot, gsum, (l < 2) ? cout : nullptr,
            (l == 2) ? out : nullptr, nullptr, 1024, 16);
        u16* tmp = cin; cin = cout; cout = tmp;
    }
}